// Round 11
// baseline (236.129 us; speedup 1.0000x reference)
//
#include <hip/hip_runtime.h>

// ---------------------------------------------------------------------------
// TTLinear on MI355X — round 10.
//   k_cvt : X, t_q, W1, W2 -> bf16 (single kernel)
//   k_q8  : Q = X @ t_q^T   256x256 8-phase counted-vmcnt. NEW: group's 24
//           ds_read_b128 all issued at p0, per-phase COUNTED lgkmcnt(12/8/0/0)
//           instead of lgkmcnt(0) — LDS latency hides under the MFMA stream.
//           Barriers/stage-placement/vmcnt(4) identical to validated R7/R10.
//   k_l1  : h2 = gelu(Q@W1^T+b1)   (proven m97 128x128)
//   k_l2  : out = Q + h2@W2^T + b2 (proven m97 128x128)
// ---------------------------------------------------------------------------

#define DD      1024
#define HH      1024
#define H4      256
#define MROWS   32768          // T*N = 128*256

typedef unsigned short u16;
typedef __bf16 bf16x8 __attribute__((ext_vector_type(8)));
typedef float  f32x4  __attribute__((ext_vector_type(4)));

__device__ __forceinline__ u16 f2b(float x) {            // fp32 -> bf16 (RNE)
  unsigned u = __builtin_bit_cast(unsigned, x);
  unsigned r = (u + 0x7fffu + ((u >> 16) & 1u)) >> 16;
  return (u16)r;
}
__device__ __forceinline__ float b2f(u16 x) {
  return __builtin_bit_cast(float, ((unsigned)x) << 16);
}

__device__ __forceinline__ void gload16(const u16* g, u16* l) {
  __builtin_amdgcn_global_load_lds(
      (const __attribute__((address_space(1))) unsigned int*)g,
      (__attribute__((address_space(3))) unsigned int*)l, 16, 0, 0);
}

// ---------------------------------------------------------------------------
// fp32 -> bf16 bulk convert, 8 elems/thread; all four tensors in one launch.
// ---------------------------------------------------------------------------
__device__ __forceinline__ void cvt8_at(u16* dst, const float* src, size_t i) {
  const float4* s = (const float4*)(src + i);
  const float4 f0 = s[0], f1 = s[1];
  uint4 pk;
  pk.x = (unsigned)f2b(f0.x) | ((unsigned)f2b(f0.y) << 16);
  pk.y = (unsigned)f2b(f0.z) | ((unsigned)f2b(f0.w) << 16);
  pk.z = (unsigned)f2b(f1.x) | ((unsigned)f2b(f1.y) << 16);
  pk.w = (unsigned)f2b(f1.z) | ((unsigned)f2b(f1.w) << 16);
  *(uint4*)(dst + i) = pk;
}

__global__ __launch_bounds__(256) void k_cvt(
    const float* __restrict__ X, const float* __restrict__ tq,
    const float* __restrict__ W1, const float* __restrict__ W2,
    u16* __restrict__ Xb, u16* __restrict__ tqb,
    u16* __restrict__ W1b, u16* __restrict__ W2b) {
  const int b = blockIdx.x;
  if (b < 16384)      cvt8_at(Xb,  X,  ((size_t)b * 256 + threadIdx.x) * 8);
  else if (b < 16896) cvt8_at(tqb, tq, ((size_t)(b - 16384) * 256 + threadIdx.x) * 8);
  else if (b < 17024) cvt8_at(W1b, W1, ((size_t)(b - 16896) * 256 + threadIdx.x) * 8);
  else                cvt8_at(W2b, W2, ((size_t)(b - 17024) * 256 + threadIdx.x) * 8);
}

// ---------------------------------------------------------------------------
// k_q8 building blocks
// ---------------------------------------------------------------------------
#define STA(s, h, kt)                                                         \
  { gload16(Ag + (size_t)((h)*128      + w*8 + srow) * 1024 + (kt)*64 + scol, \
            &sA[s][((h)*128      + w*8) * 64]);                               \
    gload16(Ag + (size_t)((h)*128 + 64 + w*8 + srow) * 1024 + (kt)*64 + scol, \
            &sA[s][((h)*128 + 64 + w*8) * 64]); }

#define STB(s, h, kt)                                                         \
  { gload16(Bg + (size_t)((h)*128      + w*8 + srow) * 1024 + (kt)*64 + scol, \
            &sB[s][((h)*128      + w*8) * 64]);                               \
    gload16(Bg + (size_t)((h)*128 + 64 + w*8 + srow) * 1024 + (kt)*64 + scol, \
            &sB[s][((h)*128 + 64 + w*8) * 64]); }

#define RD_A(s, h, dst)                                                       \
  _Pragma("unroll")                                                           \
  for (int mi = 0; mi < 4; ++mi) {                                            \
    const int row = (h)*128 + wm*64 + mi*16 + lr;                             \
    const u16* rp = &sA[s][row * 64];                                         \
    dst[mi][0] = *(const bf16x8*)(rp + (((lg    ) ^ (row & 7)) << 3));        \
    dst[mi][1] = *(const bf16x8*)(rp + (((lg + 4) ^ (row & 7)) << 3));        \
  }

#define RD_B(s, h, dst)                                                       \
  _Pragma("unroll")                                                           \
  for (int ni = 0; ni < 2; ++ni) {                                            \
    const int row = (h)*128 + wn*32 + ni*16 + lr;                             \
    const u16* rp = &sB[s][row * 64];                                         \
    dst[ni][0] = *(const bf16x8*)(rp + (((lg    ) ^ (row & 7)) << 3));        \
    dst[ni][1] = *(const bf16x8*)(rp + (((lg + 4) ^ (row & 7)) << 3));        \
  }

#define MFMA_Q(MH, NH, AF, BG)                                                \
  _Pragma("unroll")                                                           \
  for (int ks = 0; ks < 2; ++ks)                                              \
    _Pragma("unroll")                                                         \
    for (int mi = 0; mi < 4; ++mi)                                            \
      _Pragma("unroll")                                                       \
      for (int ni = 0; ni < 2; ++ni)                                          \
        acc[(MH)*4+mi][(NH)*2+ni] = __builtin_amdgcn_mfma_f32_16x16x32_bf16(  \
            AF[mi][ks], BG[ni][ks], acc[(MH)*4+mi][(NH)*2+ni], 0, 0, 0);

#define SBAR  __builtin_amdgcn_sched_barrier(0);

// Group G_j (slot u = j&1). All 24 ds_reads issued at p0 (slot-u data is
// fully landed: group j-1's p3 vmcnt(4) retired every stage into slot u).
// Counted lgkmcnt before each MFMA quadrant (issue order afr0:8, bgr0:4,
// bgr1:4, afr1:8):  p0 lgkm(12)=afr0+bgr0, p1 lgkm(8)=+bgr1, p2/p3 lgkm(0).
// Stage placement and vmcnt(4) identical to R7/R10 (race-proof):
//   p0/p1 -> slot u^1 tile j+1 {A1,B1}; p2/p3 -> slot u tile j+2 {A0,B0}
//   (A0/B0 reads lgkm-retired before MFMA0 at p0 < p2/p3 stage issue).
#define GROUP(u, j)                                                           \
  {                                                                           \
    bf16x8 afr0[4][2], afr1[4][2], bgr0[2][2], bgr1[2][2];                    \
    /* p0 */                                                                  \
    RD_A(u, 0, afr0)                                                          \
    RD_B(u, 0, bgr0)                                                          \
    RD_B(u, 1, bgr1)                                                          \
    RD_A(u, 1, afr1)                                                          \
    SBAR                                                                      \
    STA(u^1, 1, ((j)+1) & 15);                                                \
    SBAR                                                                      \
    __builtin_amdgcn_s_barrier();                                             \
    asm volatile("s_waitcnt lgkmcnt(12)" ::: "memory");                       \
    SBAR                                                                      \
    __builtin_amdgcn_s_setprio(1);                                            \
    MFMA_Q(0, 0, afr0, bgr0)                                                  \
    __builtin_amdgcn_s_setprio(0);                                            \
    SBAR                                                                      \
    __builtin_amdgcn_s_barrier();                                             \
    /* p1 */                                                                  \
    STB(u^1, 1, ((j)+1) & 15);                                                \
    SBAR                                                                      \
    __builtin_amdgcn_s_barrier();                                             \
    asm volatile("s_waitcnt lgkmcnt(8)" ::: "memory");                        \
    SBAR                                                                      \
    __builtin_amdgcn_s_setprio(1);                                            \
    MFMA_Q(0, 1, afr0, bgr1)                                                  \
    __builtin_amdgcn_s_setprio(0);                                            \
    SBAR                                                                      \
    __builtin_amdgcn_s_barrier();                                             \
    /* p2 */                                                                  \
    STA(u, 0, ((j)+2) & 15);                                                  \
    SBAR                                                                      \
    __builtin_amdgcn_s_barrier();                                             \
    asm volatile("s_waitcnt lgkmcnt(0)" ::: "memory");                        \
    SBAR                                                                      \
    __builtin_amdgcn_s_setprio(1);                                            \
    MFMA_Q(1, 1, afr1, bgr1)                                                  \
    __builtin_amdgcn_s_setprio(0);                                            \
    SBAR                                                                      \
    __builtin_amdgcn_s_barrier();                                             \
    /* p3 (no ds_reads, regs resident) */                                     \
    STB(u, 0, ((j)+2) & 15);                                                  \
    SBAR                                                                      \
    __builtin_amdgcn_s_barrier();                                             \
    SBAR                                                                      \
    __builtin_amdgcn_s_setprio(1);                                            \
    MFMA_Q(1, 0, afr1, bgr0)                                                  \
    __builtin_amdgcn_s_setprio(0);                                            \
    SBAR                                                                      \
    asm volatile("s_waitcnt vmcnt(4)" ::: "memory");                          \
    __builtin_amdgcn_s_barrier();                                             \
    SBAR                                                                      \
  }

__global__ __launch_bounds__(512, 2) void k_q8(
    const u16* __restrict__ A, const u16* __restrict__ B, u16* __restrict__ C)
{
  __shared__ u16 sA[2][256 * 64];
  __shared__ u16 sB[2][256 * 64];
  const int tid  = threadIdx.x;
  const int m0   = blockIdx.x * 256, n0 = blockIdx.y * 256;
  const int lane = tid & 63, w = tid >> 6;        // 8 waves
  const int wm = w >> 2, wn = w & 3;              // 2M x 4N wave grid
  const int lr = lane & 15, lg = lane >> 4;
  const int srow = lane >> 3;                     // staging row-in-8
  const int scol = ((lane & 7) ^ srow) << 3;      // pre-swizzled src col (u16)
  const u16* Ag = A + (size_t)m0 * 1024;
  const u16* Bg = B + (size_t)n0 * 1024;

  f32x4 acc[8][4];
  #pragma unroll
  for (int i = 0; i < 8; ++i)
    #pragma unroll
    for (int j = 0; j < 4; ++j) { f32x4 z = {0.f, 0.f, 0.f, 0.f}; acc[i][j] = z; }

  // Prologue: slot0 = tile0 complete (8 loads) + slot1 tile1 {A0,B0} (4).
  STA(0, 0, 0); STB(0, 0, 0); STA(0, 1, 0); STB(0, 1, 0);
  STA(1, 0, 1); STB(1, 0, 1);
  asm volatile("s_waitcnt vmcnt(4)" ::: "memory");   // slot0 fully landed
  __builtin_amdgcn_s_barrier();
  __builtin_amdgcn_sched_barrier(0);

  #pragma unroll 1
  for (int t = 0; t < 8; ++t) {
    GROUP(0, 2 * t)
    GROUP(1, 2 * t + 1)
  }
  asm volatile("s_waitcnt vmcnt(0)" ::: "memory");

  #pragma unroll
  for (int im = 0; im < 8; ++im)
    #pragma unroll
    for (int in = 0; in < 4; ++in)
      #pragma unroll
      for (int r = 0; r < 4; ++r) {
        const int grow = m0 + (im >> 2) * 128 + wm * 64 + (im & 3) * 16 + lg * 4 + r;
        const int gcol = n0 + (in >> 1) * 128 + wn * 32 + (in & 1) * 16 + lr;
        C[(size_t)grow * HH + gcol] = f2b(acc[im][in][r]);
      }
}

// ---------------------------------------------------------------------------
// Proven m97 128x128 GEMM (k_l1 / k_l2).
// MODE 1: gelu -> bf16.  MODE 2: fp32 residual + bias.
// ---------------------------------------------------------------------------
template<int MODE, int LDA, int LDB, int K, int LDC>
__global__ __launch_bounds__(256) void k_gemm(
    const u16* __restrict__ A, const u16* __restrict__ B,
    const float* __restrict__ bias, const u16* __restrict__ Qb,
    u16* __restrict__ outb, float* __restrict__ outf)
{
  __shared__ u16 smA[128 * 64];
  __shared__ u16 smB[128 * 64];
  const int tid  = threadIdx.x;
  const int m0   = blockIdx.x * 128, n0 = blockIdx.y * 128;
  const int lane = tid & 63, w = tid >> 6;
  const int wr = w >> 1, wc = w & 1;
  const int lr = lane & 15, lg = lane >> 4;

  const int r0 = w * 8 + (lane >> 3);
  const int cb = (lane & 7) ^ (r0 & 7);
  const u16* ga = A + (size_t)(m0 + r0) * LDA + cb * 8;
  const u16* gb = B + (size_t)(n0 + r0) * LDB + cb * 8;
  u16* lA = smA + w * 512;
  u16* lB = smB + w * 512;

  f32x4 acc[4][4];
  #pragma unroll
  for (int i = 0; i < 4; ++i)
    #pragma unroll
    for (int j = 0; j < 4; ++j) { f32x4 z = {0.f, 0.f, 0.f, 0.f}; acc[i][j] = z; }

  for (int k0 = 0; k0 < K; k0 += 64) {
    #pragma unroll
    for (int j = 0; j < 4; ++j) {
      gload16(ga + (size_t)j * 32 * LDA + k0, lA + j * 2048);
      gload16(gb + (size_t)j * 32 * LDB + k0, lB + j * 2048);
    }
    __syncthreads();
    #pragma unroll
    for (int kc = 0; kc < 2; ++kc) {
      const int blk = kc * 4 + lg;
      bf16x8 af[4], bg[4];
      #pragma unroll
      for (int mi = 0; mi < 4; ++mi) {
        const int row = wr * 64 + mi * 16 + lr;
        af[mi] = *(const bf16x8*)&smA[row * 64 + ((blk ^ (row & 7)) << 3)];
      }
      #pragma unroll
      for (int ni = 0; ni < 4; ++ni) {
        const int row = wc * 64 + ni * 16 + lr;
        bg[ni] = *(const bf16x8*)&smB[row * 64 + ((blk ^ (row & 7)) << 3)];
      }
      #pragma unroll
      for (int mi = 0; mi < 4; ++mi)
        #pragma unroll
        for (int ni = 0; ni < 4; ++ni)
          acc[mi][ni] = __builtin_amdgcn_mfma_f32_16x16x32_bf16(
              af[mi], bg[ni], acc[mi][ni], 0, 0, 0);
    }
    __syncthreads();
  }

  #pragma unroll
  for (int mi = 0; mi < 4; ++mi)
    #pragma unroll
    for (int ni = 0; ni < 4; ++ni)
      #pragma unroll
      for (int r = 0; r < 4; ++r) {
        const int grow = m0 + wr * 64 + mi * 16 + lg * 4 + r;
        const int gcol = n0 + wc * 64 + ni * 16 + lr;
        const size_t idx = (size_t)grow * LDC + gcol;
        if (MODE == 1) {
          const float a = acc[mi][ni][r] + bias[gcol];
          const float cdf = 0.5f * (1.0f + erff(a * 0.70710678118654752f));
          outb[idx] = f2b(a * cdf);
        } else {
          outf[idx] = b2f(Qb[idx]) + acc[mi][ni][r] + bias[gcol];
        }
      }
}

// ---------------------------------------------------------------------------
extern "C" void kernel_launch(void* const* d_in, const int* in_sizes, int n_in,
                              void* d_out, int out_size, void* d_ws, size_t ws_size,
                              hipStream_t stream)
{
  const float* in_seq = (const float*)d_in[0];
  const float* t_q = (const float*)d_in[3];
  const float* W1  = (const float*)d_in[4];
  const float* b1  = (const float*)d_in[5];
  const float* W2  = (const float*)d_in[6];
  const float* b2  = (const float*)d_in[7];
  float* out = (float*)d_out;

  char* p = (char*)d_ws;
  u16* Xb  = (u16*)p;  p += (size_t)MROWS * DD * sizeof(u16);   // 64 MiB
  u16* Qb  = (u16*)p;  p += (size_t)MROWS * HH * sizeof(u16);   // 64 MiB
  u16* Wqb = (u16*)p;  p += (size_t)HH * DD * sizeof(u16);      // 2 MiB
  u16* W1b = (u16*)p;  p += (size_t)H4 * HH * sizeof(u16);
  u16* W2b = (u16*)p;  p += (size_t)HH * H4 * sizeof(u16);
  u16* h2  = Xb;                                                // alias

  k_cvt<<<17152, 256, 0, stream>>>(in_seq, t_q, W1, W2, Xb, Wqb, W1b, W2b);

  // Q = X @ t_q^T   (8-phase 256x256, hoisted ds_reads + counted lgkmcnt)
  k_q8<<<dim3(128, 4), 512, 0, stream>>>(Xb, Wqb, Qb);
  // h2 = gelu(Q @ W1^T + b1)
  k_gemm<1, HH, HH, HH, H4><<<dim3(256, 2), 256, 0, stream>>>(
      Qb, W1b, b1, nullptr, h2, nullptr);
  // out = Q + h2 @ W2^T + b2
  k_gemm<2, H4, H4, H4, HH><<<dim3(256, 8), 256, 0, stream>>>(
      h2, W2b, b2, Qb, nullptr, out);
}

// Round 12
// 220.510 us; speedup vs baseline: 1.0708x; 1.0708x over previous
//
#include <hip/hip_runtime.h>

// ---------------------------------------------------------------------------
// TTLinear on MI355X — round 11: consolidation to all-proven components.
//   k_cvt : X, t_q, W1, W2 -> bf16 (single kernel, memory-floor)
//   k_q   : Q = X @ t_q^T          (m97 128x128, 86us measured — the 256x256
//           8-phase attempts are retired: R6 race, R9 LDS-bound 105us,
//           R10 snake 88.6us, R11 hoist spilled 107us; best never beat 86)
//   k_l1  : h2 = gelu(Q@W1^T+b1)   (proven m97 128x128)
//   k_l2  : out = Q + h2@W2^T + b2 (proven m97 128x128, near mem floor)
// ---------------------------------------------------------------------------

#define DD      1024
#define HH      1024
#define H4      256
#define MROWS   32768          // T*N = 128*256

typedef unsigned short u16;
typedef __bf16 bf16x8 __attribute__((ext_vector_type(8)));
typedef float  f32x4  __attribute__((ext_vector_type(4)));

__device__ __forceinline__ u16 f2b(float x) {            // fp32 -> bf16 (RNE)
  unsigned u = __builtin_bit_cast(unsigned, x);
  unsigned r = (u + 0x7fffu + ((u >> 16) & 1u)) >> 16;
  return (u16)r;
}
__device__ __forceinline__ float b2f(u16 x) {
  return __builtin_bit_cast(float, ((unsigned)x) << 16);
}

__device__ __forceinline__ void gload16(const u16* g, u16* l) {
  __builtin_amdgcn_global_load_lds(
      (const __attribute__((address_space(1))) unsigned int*)g,
      (__attribute__((address_space(3))) unsigned int*)l, 16, 0, 0);
}

// ---------------------------------------------------------------------------
// fp32 -> bf16 bulk convert, 8 elems/thread; all four tensors in one launch.
// blocks: [0,16384) X | [16384,16896) t_q | [16896,17024) W1 | [17024,17152) W2
// ---------------------------------------------------------------------------
__device__ __forceinline__ void cvt8_at(u16* dst, const float* src, size_t i) {
  const float4* s = (const float4*)(src + i);
  const float4 f0 = s[0], f1 = s[1];
  uint4 pk;
  pk.x = (unsigned)f2b(f0.x) | ((unsigned)f2b(f0.y) << 16);
  pk.y = (unsigned)f2b(f0.z) | ((unsigned)f2b(f0.w) << 16);
  pk.z = (unsigned)f2b(f1.x) | ((unsigned)f2b(f1.y) << 16);
  pk.w = (unsigned)f2b(f1.z) | ((unsigned)f2b(f1.w) << 16);
  *(uint4*)(dst + i) = pk;
}

__global__ __launch_bounds__(256) void k_cvt(
    const float* __restrict__ X, const float* __restrict__ tq,
    const float* __restrict__ W1, const float* __restrict__ W2,
    u16* __restrict__ Xb, u16* __restrict__ tqb,
    u16* __restrict__ W1b, u16* __restrict__ W2b) {
  const int b = blockIdx.x;
  if (b < 16384)      cvt8_at(Xb,  X,  ((size_t)b * 256 + threadIdx.x) * 8);
  else if (b < 16896) cvt8_at(tqb, tq, ((size_t)(b - 16384) * 256 + threadIdx.x) * 8);
  else if (b < 17024) cvt8_at(W1b, W1, ((size_t)(b - 16896) * 256 + threadIdx.x) * 8);
  else                cvt8_at(W2b, W2, ((size_t)(b - 17024) * 256 + threadIdx.x) * 8);
}

// ---------------------------------------------------------------------------
// m97 128x128 bf16 MFMA GEMM (global_load_lds width=16, linear LDS dest,
// pre-swizzled global source, XOR'd ds_read; 2-barrier K-loop).
//   C(m,n) = sum_k A[m][k] * B[n][k]
// MODE 0: bf16 store.  MODE 1: gelu -> bf16.  MODE 2: fp32 residual + bias.
// ---------------------------------------------------------------------------
template<int MODE, int LDA, int LDB, int K, int LDC>
__global__ __launch_bounds__(256) void k_gemm(
    const u16* __restrict__ A, const u16* __restrict__ B,
    const float* __restrict__ bias, const u16* __restrict__ Qb,
    u16* __restrict__ outb, float* __restrict__ outf)
{
  __shared__ u16 smA[128 * 64];
  __shared__ u16 smB[128 * 64];
  const int tid  = threadIdx.x;
  const int m0   = blockIdx.x * 128, n0 = blockIdx.y * 128;
  const int lane = tid & 63, w = tid >> 6;
  const int wr = w >> 1, wc = w & 1;
  const int lr = lane & 15, lg = lane >> 4;

  const int r0 = w * 8 + (lane >> 3);
  const int cb = (lane & 7) ^ (r0 & 7);
  const u16* ga = A + (size_t)(m0 + r0) * LDA + cb * 8;
  const u16* gb = B + (size_t)(n0 + r0) * LDB + cb * 8;
  u16* lA = smA + w * 512;
  u16* lB = smB + w * 512;

  f32x4 acc[4][4];
  #pragma unroll
  for (int i = 0; i < 4; ++i)
    #pragma unroll
    for (int j = 0; j < 4; ++j) { f32x4 z = {0.f, 0.f, 0.f, 0.f}; acc[i][j] = z; }

  for (int k0 = 0; k0 < K; k0 += 64) {
    #pragma unroll
    for (int j = 0; j < 4; ++j) {
      gload16(ga + (size_t)j * 32 * LDA + k0, lA + j * 2048);
      gload16(gb + (size_t)j * 32 * LDB + k0, lB + j * 2048);
    }
    __syncthreads();
    #pragma unroll
    for (int kc = 0; kc < 2; ++kc) {
      const int blk = kc * 4 + lg;
      bf16x8 af[4], bg[4];
      #pragma unroll
      for (int mi = 0; mi < 4; ++mi) {
        const int row = wr * 64 + mi * 16 + lr;
        af[mi] = *(const bf16x8*)&smA[row * 64 + ((blk ^ (row & 7)) << 3)];
      }
      #pragma unroll
      for (int ni = 0; ni < 4; ++ni) {
        const int row = wc * 64 + ni * 16 + lr;
        bg[ni] = *(const bf16x8*)&smB[row * 64 + ((blk ^ (row & 7)) << 3)];
      }
      #pragma unroll
      for (int mi = 0; mi < 4; ++mi)
        #pragma unroll
        for (int ni = 0; ni < 4; ++ni)
          acc[mi][ni] = __builtin_amdgcn_mfma_f32_16x16x32_bf16(
              af[mi], bg[ni], acc[mi][ni], 0, 0, 0);
    }
    __syncthreads();
  }

  #pragma unroll
  for (int mi = 0; mi < 4; ++mi)
    #pragma unroll
    for (int ni = 0; ni < 4; ++ni)
      #pragma unroll
      for (int r = 0; r < 4; ++r) {
        const int grow = m0 + wr * 64 + mi * 16 + lg * 4 + r;
        const int gcol = n0 + wc * 64 + ni * 16 + lr;
        const size_t idx = (size_t)grow * LDC + gcol;
        if (MODE == 0) {
          outb[idx] = f2b(acc[mi][ni][r]);
        } else if (MODE == 1) {
          const float a = acc[mi][ni][r] + bias[gcol];
          const float cdf = 0.5f * (1.0f + erff(a * 0.70710678118654752f));
          outb[idx] = f2b(a * cdf);
        } else {
          outf[idx] = b2f(Qb[idx]) + acc[mi][ni][r] + bias[gcol];
        }
      }
}

// ---------------------------------------------------------------------------
extern "C" void kernel_launch(void* const* d_in, const int* in_sizes, int n_in,
                              void* d_out, int out_size, void* d_ws, size_t ws_size,
                              hipStream_t stream)
{
  const float* in_seq = (const float*)d_in[0];
  const float* t_q = (const float*)d_in[3];
  const float* W1  = (const float*)d_in[4];
  const float* b1  = (const float*)d_in[5];
  const float* W2  = (const float*)d_in[6];
  const float* b2  = (const float*)d_in[7];
  float* out = (float*)d_out;

  char* p = (char*)d_ws;
  u16* Xb  = (u16*)p;  p += (size_t)MROWS * DD * sizeof(u16);   // 64 MiB
  u16* Qb  = (u16*)p;  p += (size_t)MROWS * HH * sizeof(u16);   // 64 MiB
  u16* Wqb = (u16*)p;  p += (size_t)HH * DD * sizeof(u16);      // 2 MiB
  u16* W1b = (u16*)p;  p += (size_t)H4 * HH * sizeof(u16);
  u16* W2b = (u16*)p;  p += (size_t)HH * H4 * sizeof(u16);
  u16* h2  = Xb;                                                // alias

  k_cvt<<<17152, 256, 0, stream>>>(in_seq, t_q, W1, W2, Xb, Wqb, W1b, W2b);

  // Q = X @ t_q^T
  k_gemm<0, DD, DD, DD, HH><<<dim3(256, 8), 256, 0, stream>>>(
      Xb, Wqb, nullptr, nullptr, Qb, nullptr);
  // h2 = gelu(Q @ W1^T + b1)
  k_gemm<1, HH, HH, HH, H4><<<dim3(256, 2), 256, 0, stream>>>(
      Qb, W1b, b1, nullptr, h2, nullptr);
  // out = Q + h2 @ W2^T + b2
  k_gemm<2, H4, H4, H4, HH><<<dim3(256, 8), 256, 0, stream>>>(
      h2, W2b, b2, Qb, nullptr, out);
}

// Round 13
// 213.813 us; speedup vs baseline: 1.1044x; 1.0313x over previous
//
#include <hip/hip_runtime.h>

// ---------------------------------------------------------------------------
// TTLinear on MI355X — round 12: vectorized epilogues via MFMA operand swap.
// D-layout: reg-axis (4 consecutive) follows the *first* operand; passing
// B-fragments as 'a' and A-fragments as 'b' gives each lane 4 consecutive
// OUTPUT COLUMNS of one row -> ushort4/float4 epilogue loads+stores.
//   k_cvt : X, t_q, W1, W2 -> bf16
//   k_q   : Q = X @ t_q^T          (m97 128x128, swapped epilogue, bf16x4 st)
//   k_l1  : h2 = gelu(Q@W1^T+b1)   (same, bf16x4 st, float4 bias)
//   k_l2  : out = Q + h2@W2^T + b2 (same, ushort4 residual rd, float4 st)
// ---------------------------------------------------------------------------

#define DD      1024
#define HH      1024
#define H4      256
#define MROWS   32768          // T*N = 128*256

typedef unsigned short u16;
typedef __bf16 bf16x8 __attribute__((ext_vector_type(8)));
typedef float  f32x4  __attribute__((ext_vector_type(4)));

__device__ __forceinline__ u16 f2b(float x) {            // fp32 -> bf16 (RNE)
  unsigned u = __builtin_bit_cast(unsigned, x);
  unsigned r = (u + 0x7fffu + ((u >> 16) & 1u)) >> 16;
  return (u16)r;
}
__device__ __forceinline__ float b2f(u16 x) {
  return __builtin_bit_cast(float, ((unsigned)x) << 16);
}

__device__ __forceinline__ void gload16(const u16* g, u16* l) {
  __builtin_amdgcn_global_load_lds(
      (const __attribute__((address_space(1))) unsigned int*)g,
      (__attribute__((address_space(3))) unsigned int*)l, 16, 0, 0);
}

// ---------------------------------------------------------------------------
// fp32 -> bf16 bulk convert, 8 elems/thread; all four tensors in one launch.
// ---------------------------------------------------------------------------
__device__ __forceinline__ void cvt8_at(u16* dst, const float* src, size_t i) {
  const float4* s = (const float4*)(src + i);
  const float4 f0 = s[0], f1 = s[1];
  uint4 pk;
  pk.x = (unsigned)f2b(f0.x) | ((unsigned)f2b(f0.y) << 16);
  pk.y = (unsigned)f2b(f0.z) | ((unsigned)f2b(f0.w) << 16);
  pk.z = (unsigned)f2b(f1.x) | ((unsigned)f2b(f1.y) << 16);
  pk.w = (unsigned)f2b(f1.z) | ((unsigned)f2b(f1.w) << 16);
  *(uint4*)(dst + i) = pk;
}

__global__ __launch_bounds__(256) void k_cvt(
    const float* __restrict__ X, const float* __restrict__ tq,
    const float* __restrict__ W1, const float* __restrict__ W2,
    u16* __restrict__ Xb, u16* __restrict__ tqb,
    u16* __restrict__ W1b, u16* __restrict__ W2b) {
  const int b = blockIdx.x;
  if (b < 16384)      cvt8_at(Xb,  X,  ((size_t)b * 256 + threadIdx.x) * 8);
  else if (b < 16896) cvt8_at(tqb, tq, ((size_t)(b - 16384) * 256 + threadIdx.x) * 8);
  else if (b < 17024) cvt8_at(W1b, W1, ((size_t)(b - 16896) * 256 + threadIdx.x) * 8);
  else                cvt8_at(W2b, W2, ((size_t)(b - 17024) * 256 + threadIdx.x) * 8);
}

// ---------------------------------------------------------------------------
// m97 128x128 bf16 MFMA GEMM, swapped-operand epilogue.
//   C(m,n) = sum_k A[m][k] * B[n][k]
// mfma(bF[ni], aF[mi], acc) -> lane(lg,lr) of acc[mi][ni] holds
//   m = m0 + wr*64 + mi*16 + lr          (lane axis)
//   n = n0 + wc*64 + ni*16 + lg*4 + r    (reg axis: 4 consecutive cols)
// MODE 0: bf16x4 store.  MODE 1: gelu -> bf16x4.  MODE 2: fp32x4 residual.
// ---------------------------------------------------------------------------
template<int MODE, int LDA, int LDB, int K, int LDC>
__global__ __launch_bounds__(256) void k_gemm(
    const u16* __restrict__ A, const u16* __restrict__ B,
    const float* __restrict__ bias, const u16* __restrict__ Qb,
    u16* __restrict__ outb, float* __restrict__ outf)
{
  __shared__ u16 smA[128 * 64];
  __shared__ u16 smB[128 * 64];
  const int tid  = threadIdx.x;
  const int m0   = blockIdx.x * 128, n0 = blockIdx.y * 128;
  const int lane = tid & 63, w = tid >> 6;
  const int wr = w >> 1, wc = w & 1;
  const int lr = lane & 15, lg = lane >> 4;

  const int r0 = w * 8 + (lane >> 3);
  const int cb = (lane & 7) ^ (r0 & 7);
  const u16* ga = A + (size_t)(m0 + r0) * LDA + cb * 8;
  const u16* gb = B + (size_t)(n0 + r0) * LDB + cb * 8;
  u16* lA = smA + w * 512;
  u16* lB = smB + w * 512;

  f32x4 acc[4][4];
  #pragma unroll
  for (int i = 0; i < 4; ++i)
    #pragma unroll
    for (int j = 0; j < 4; ++j) { f32x4 z = {0.f, 0.f, 0.f, 0.f}; acc[i][j] = z; }

  for (int k0 = 0; k0 < K; k0 += 64) {
    #pragma unroll
    for (int j = 0; j < 4; ++j) {
      gload16(ga + (size_t)j * 32 * LDA + k0, lA + j * 2048);
      gload16(gb + (size_t)j * 32 * LDB + k0, lB + j * 2048);
    }
    __syncthreads();
    #pragma unroll
    for (int kc = 0; kc < 2; ++kc) {
      const int blk = kc * 4 + lg;
      bf16x8 aF[4], bF[4];
      #pragma unroll
      for (int mi = 0; mi < 4; ++mi) {
        const int row = wr * 64 + mi * 16 + lr;
        aF[mi] = *(const bf16x8*)&smA[row * 64 + ((blk ^ (row & 7)) << 3)];
      }
      #pragma unroll
      for (int ni = 0; ni < 4; ++ni) {
        const int row = wc * 64 + ni * 16 + lr;
        bF[ni] = *(const bf16x8*)&smB[row * 64 + ((blk ^ (row & 7)) << 3)];
      }
      #pragma unroll
      for (int mi = 0; mi < 4; ++mi)
        #pragma unroll
        for (int ni = 0; ni < 4; ++ni)
          acc[mi][ni] = __builtin_amdgcn_mfma_f32_16x16x32_bf16(
              bF[ni], aF[mi], acc[mi][ni], 0, 0, 0);   // swapped: reg axis = n
    }
    __syncthreads();
  }

  #pragma unroll
  for (int mi = 0; mi < 4; ++mi) {
    const int m = m0 + wr * 64 + mi * 16 + lr;
    #pragma unroll
    for (int ni = 0; ni < 4; ++ni) {
      const int nb = n0 + wc * 64 + ni * 16 + lg * 4;
      const size_t idx = (size_t)m * LDC + nb;
      if (MODE == 0) {
        ushort4 v;
        v.x = f2b(acc[mi][ni][0]); v.y = f2b(acc[mi][ni][1]);
        v.z = f2b(acc[mi][ni][2]); v.w = f2b(acc[mi][ni][3]);
        *(ushort4*)&outb[idx] = v;
      } else if (MODE == 1) {
        const float4 b4 = *(const float4*)&bias[nb];
        ushort4 v;
        #pragma unroll
        for (int r = 0; r < 4; ++r) {
          const float a = acc[mi][ni][r] + ((const float*)&b4)[r];
          const float cdf = 0.5f * (1.0f + erff(a * 0.70710678118654752f));
          ((u16*)&v)[r] = f2b(a * cdf);
        }
        *(ushort4*)&outb[idx] = v;
      } else {
        const float4 b4 = *(const float4*)&bias[nb];
        const ushort4 q4 = *(const ushort4*)&Qb[idx];
        float4 o;
        o.x = b2f(q4.x) + acc[mi][ni][0] + b4.x;
        o.y = b2f(q4.y) + acc[mi][ni][1] + b4.y;
        o.z = b2f(q4.z) + acc[mi][ni][2] + b4.z;
        o.w = b2f(q4.w) + acc[mi][ni][3] + b4.w;
        *(float4*)&outf[idx] = o;
      }
    }
  }
}

// ---------------------------------------------------------------------------
extern "C" void kernel_launch(void* const* d_in, const int* in_sizes, int n_in,
                              void* d_out, int out_size, void* d_ws, size_t ws_size,
                              hipStream_t stream)
{
  const float* in_seq = (const float*)d_in[0];
  const float* t_q = (const float*)d_in[3];
  const float* W1  = (const float*)d_in[4];
  const float* b1  = (const float*)d_in[5];
  const float* W2  = (const float*)d_in[6];
  const float* b2  = (const float*)d_in[7];
  float* out = (float*)d_out;

  char* p = (char*)d_ws;
  u16* Xb  = (u16*)p;  p += (size_t)MROWS * DD * sizeof(u16);   // 64 MiB
  u16* Qb  = (u16*)p;  p += (size_t)MROWS * HH * sizeof(u16);   // 64 MiB
  u16* Wqb = (u16*)p;  p += (size_t)HH * DD * sizeof(u16);      // 2 MiB
  u16* W1b = (u16*)p;  p += (size_t)H4 * HH * sizeof(u16);
  u16* W2b = (u16*)p;  p += (size_t)HH * H4 * sizeof(u16);
  u16* h2  = Xb;                                                // alias

  k_cvt<<<17152, 256, 0, stream>>>(in_seq, t_q, W1, W2, Xb, Wqb, W1b, W2b);

  // Q = X @ t_q^T
  k_gemm<0, DD, DD, DD, HH><<<dim3(256, 8), 256, 0, stream>>>(
      Xb, Wqb, nullptr, nullptr, Qb, nullptr);
  // h2 = gelu(Q @ W1^T + b1)
  k_gemm<1, HH, HH, HH, H4><<<dim3(256, 2), 256, 0, stream>>>(
      Qb, W1b, b1, nullptr, h2, nullptr);
  // out = Q + h2 @ W2^T + b2
  k_gemm<2, H4, H4, H4, HH><<<dim3(256, 8), 256, 0, stream>>>(
      h2, W2b, b2, Qb, nullptr, out);
}

// Round 14
// 203.277 us; speedup vs baseline: 1.1616x; 1.0518x over previous
//
#include <hip/hip_runtime.h>

// ---------------------------------------------------------------------------
// TTLinear on MI355X — round 13: best-of-both epilogues.
// R13 measured: swapped epilogue (per-lane float4/ushort4, reg axis = cols)
// HURT k_q (scattered 8B stores -> +28MB write-allocate, 86.5->100us) but
// HELPED l1/l2 (~-20us). So: k_q = unswapped (coalesced scalar stores),
// l1/l2 = swapped (vector residual/bias/store).
//   k_cvt : X, t_q, W1, W2 -> bf16
//   k_q   : Q = X @ t_q^T          (m97 128x128, UNSWAPPED, 86.5us proven)
//   k_l1  : h2 = gelu(Q@W1^T+b1)   (swapped)
//   k_l2  : out = Q + h2@W2^T + b2 (swapped)
// ---------------------------------------------------------------------------

#define DD      1024
#define HH      1024
#define H4      256
#define MROWS   32768          // T*N = 128*256

typedef unsigned short u16;
typedef __bf16 bf16x8 __attribute__((ext_vector_type(8)));
typedef float  f32x4  __attribute__((ext_vector_type(4)));

__device__ __forceinline__ u16 f2b(float x) {            // fp32 -> bf16 (RNE)
  unsigned u = __builtin_bit_cast(unsigned, x);
  unsigned r = (u + 0x7fffu + ((u >> 16) & 1u)) >> 16;
  return (u16)r;
}
__device__ __forceinline__ float b2f(u16 x) {
  return __builtin_bit_cast(float, ((unsigned)x) << 16);
}

__device__ __forceinline__ void gload16(const u16* g, u16* l) {
  __builtin_amdgcn_global_load_lds(
      (const __attribute__((address_space(1))) unsigned int*)g,
      (__attribute__((address_space(3))) unsigned int*)l, 16, 0, 0);
}

// ---------------------------------------------------------------------------
// fp32 -> bf16 bulk convert, 8 elems/thread; all four tensors in one launch.
// ---------------------------------------------------------------------------
__device__ __forceinline__ void cvt8_at(u16* dst, const float* src, size_t i) {
  const float4* s = (const float4*)(src + i);
  const float4 f0 = s[0], f1 = s[1];
  uint4 pk;
  pk.x = (unsigned)f2b(f0.x) | ((unsigned)f2b(f0.y) << 16);
  pk.y = (unsigned)f2b(f0.z) | ((unsigned)f2b(f0.w) << 16);
  pk.z = (unsigned)f2b(f1.x) | ((unsigned)f2b(f1.y) << 16);
  pk.w = (unsigned)f2b(f1.z) | ((unsigned)f2b(f1.w) << 16);
  *(uint4*)(dst + i) = pk;
}

__global__ __launch_bounds__(256) void k_cvt(
    const float* __restrict__ X, const float* __restrict__ tq,
    const float* __restrict__ W1, const float* __restrict__ W2,
    u16* __restrict__ Xb, u16* __restrict__ tqb,
    u16* __restrict__ W1b, u16* __restrict__ W2b) {
  const int b = blockIdx.x;
  if (b < 16384)      cvt8_at(Xb,  X,  ((size_t)b * 256 + threadIdx.x) * 8);
  else if (b < 16896) cvt8_at(tqb, tq, ((size_t)(b - 16384) * 256 + threadIdx.x) * 8);
  else if (b < 17024) cvt8_at(W1b, W1, ((size_t)(b - 16896) * 256 + threadIdx.x) * 8);
  else                cvt8_at(W2b, W2, ((size_t)(b - 17024) * 256 + threadIdx.x) * 8);
}

// ---------------------------------------------------------------------------
// m97 128x128 bf16 MFMA GEMM.  C(m,n) = sum_k A[m][k] * B[n][k]
// SWAP=0 (k_q): mfma(aF,bF): reg axis = m rows, lane axis = n cols
//               -> scalar stores, 16 lanes contiguous (coalesced).
// SWAP=1 (l1/l2): mfma(bF,aF): reg axis = n cols
//               -> per-lane ushort4/float4 epilogue.
// MODE 0: bf16 store.  MODE 1: gelu -> bf16.  MODE 2: fp32 residual + bias.
// ---------------------------------------------------------------------------
template<int MODE, int SWAP, int LDA, int LDB, int K, int LDC>
__global__ __launch_bounds__(256) void k_gemm(
    const u16* __restrict__ A, const u16* __restrict__ B,
    const float* __restrict__ bias, const u16* __restrict__ Qb,
    u16* __restrict__ outb, float* __restrict__ outf)
{
  __shared__ u16 smA[128 * 64];
  __shared__ u16 smB[128 * 64];
  const int tid  = threadIdx.x;
  const int m0   = blockIdx.x * 128, n0 = blockIdx.y * 128;
  const int lane = tid & 63, w = tid >> 6;
  const int wr = w >> 1, wc = w & 1;
  const int lr = lane & 15, lg = lane >> 4;

  const int r0 = w * 8 + (lane >> 3);
  const int cb = (lane & 7) ^ (r0 & 7);
  const u16* ga = A + (size_t)(m0 + r0) * LDA + cb * 8;
  const u16* gb = B + (size_t)(n0 + r0) * LDB + cb * 8;
  u16* lA = smA + w * 512;
  u16* lB = smB + w * 512;

  f32x4 acc[4][4];
  #pragma unroll
  for (int i = 0; i < 4; ++i)
    #pragma unroll
    for (int j = 0; j < 4; ++j) { f32x4 z = {0.f, 0.f, 0.f, 0.f}; acc[i][j] = z; }

  for (int k0 = 0; k0 < K; k0 += 64) {
    #pragma unroll
    for (int j = 0; j < 4; ++j) {
      gload16(ga + (size_t)j * 32 * LDA + k0, lA + j * 2048);
      gload16(gb + (size_t)j * 32 * LDB + k0, lB + j * 2048);
    }
    __syncthreads();
    #pragma unroll
    for (int kc = 0; kc < 2; ++kc) {
      const int blk = kc * 4 + lg;
      bf16x8 aF[4], bF[4];
      #pragma unroll
      for (int mi = 0; mi < 4; ++mi) {
        const int row = wr * 64 + mi * 16 + lr;
        aF[mi] = *(const bf16x8*)&smA[row * 64 + ((blk ^ (row & 7)) << 3)];
      }
      #pragma unroll
      for (int ni = 0; ni < 4; ++ni) {
        const int row = wc * 64 + ni * 16 + lr;
        bF[ni] = *(const bf16x8*)&smB[row * 64 + ((blk ^ (row & 7)) << 3)];
      }
      #pragma unroll
      for (int mi = 0; mi < 4; ++mi)
        #pragma unroll
        for (int ni = 0; ni < 4; ++ni) {
          if (SWAP)
            acc[mi][ni] = __builtin_amdgcn_mfma_f32_16x16x32_bf16(
                bF[ni], aF[mi], acc[mi][ni], 0, 0, 0);   // reg axis = n
          else
            acc[mi][ni] = __builtin_amdgcn_mfma_f32_16x16x32_bf16(
                aF[mi], bF[ni], acc[mi][ni], 0, 0, 0);   // reg axis = m
        }
    }
    __syncthreads();
  }

  if (!SWAP) {
    // coalesced scalar epilogue: m = reg axis, n = lane axis
    #pragma unroll
    for (int mi = 0; mi < 4; ++mi)
      #pragma unroll
      for (int ni = 0; ni < 4; ++ni)
        #pragma unroll
        for (int r = 0; r < 4; ++r) {
          const int grow = m0 + wr * 64 + mi * 16 + lg * 4 + r;
          const int gcol = n0 + wc * 64 + ni * 16 + lr;
          const size_t idx = (size_t)grow * LDC + gcol;
          if (MODE == 0) {
            outb[idx] = f2b(acc[mi][ni][r]);
          } else if (MODE == 1) {
            const float a = acc[mi][ni][r] + bias[gcol];
            const float cdf = 0.5f * (1.0f + erff(a * 0.70710678118654752f));
            outb[idx] = f2b(a * cdf);
          } else {
            outf[idx] = b2f(Qb[idx]) + acc[mi][ni][r] + bias[gcol];
          }
        }
  } else {
    // per-lane vector epilogue: n = reg axis (4 consecutive cols)
    #pragma unroll
    for (int mi = 0; mi < 4; ++mi) {
      const int m = m0 + wr * 64 + mi * 16 + lr;
      #pragma unroll
      for (int ni = 0; ni < 4; ++ni) {
        const int nb = n0 + wc * 64 + ni * 16 + lg * 4;
        const size_t idx = (size_t)m * LDC + nb;
        if (MODE == 0) {
          ushort4 v;
          v.x = f2b(acc[mi][ni][0]); v.y = f2b(acc[mi][ni][1]);
          v.z = f2b(acc[mi][ni][2]); v.w = f2b(acc[mi][ni][3]);
          *(ushort4*)&outb[idx] = v;
        } else if (MODE == 1) {
          const float4 b4 = *(const float4*)&bias[nb];
          ushort4 v;
          #pragma unroll
          for (int r = 0; r < 4; ++r) {
            const float a = acc[mi][ni][r] + ((const float*)&b4)[r];
            const float cdf = 0.5f * (1.0f + erff(a * 0.70710678118654752f));
            ((u16*)&v)[r] = f2b(a * cdf);
          }
          *(ushort4*)&outb[idx] = v;
        } else {
          const float4 b4 = *(const float4*)&bias[nb];
          const ushort4 q4 = *(const ushort4*)&Qb[idx];
          float4 o;
          o.x = b2f(q4.x) + acc[mi][ni][0] + b4.x;
          o.y = b2f(q4.y) + acc[mi][ni][1] + b4.y;
          o.z = b2f(q4.z) + acc[mi][ni][2] + b4.z;
          o.w = b2f(q4.w) + acc[mi][ni][3] + b4.w;
          *(float4*)&outf[idx] = o;
        }
      }
    }
  }
}

// ---------------------------------------------------------------------------
extern "C" void kernel_launch(void* const* d_in, const int* in_sizes, int n_in,
                              void* d_out, int out_size, void* d_ws, size_t ws_size,
                              hipStream_t stream)
{
  const float* in_seq = (const float*)d_in[0];
  const float* t_q = (const float*)d_in[3];
  const float* W1  = (const float*)d_in[4];
  const float* b1  = (const float*)d_in[5];
  const float* W2  = (const float*)d_in[6];
  const float* b2  = (const float*)d_in[7];
  float* out = (float*)d_out;

  char* p = (char*)d_ws;
  u16* Xb  = (u16*)p;  p += (size_t)MROWS * DD * sizeof(u16);   // 64 MiB
  u16* Qb  = (u16*)p;  p += (size_t)MROWS * HH * sizeof(u16);   // 64 MiB
  u16* Wqb = (u16*)p;  p += (size_t)HH * DD * sizeof(u16);      // 2 MiB
  u16* W1b = (u16*)p;  p += (size_t)H4 * HH * sizeof(u16);
  u16* W2b = (u16*)p;  p += (size_t)HH * H4 * sizeof(u16);
  u16* h2  = Xb;                                                // alias

  k_cvt<<<17152, 256, 0, stream>>>(in_seq, t_q, W1, W2, Xb, Wqb, W1b, W2b);

  // Q = X @ t_q^T   (unswapped: coalesced bf16 stores)
  k_gemm<0, 0, DD, DD, DD, HH><<<dim3(256, 8), 256, 0, stream>>>(
      Xb, Wqb, nullptr, nullptr, Qb, nullptr);
  // h2 = gelu(Q @ W1^T + b1)   (swapped: vector epilogue)
  k_gemm<1, 1, HH, HH, HH, H4><<<dim3(256, 2), 256, 0, stream>>>(
      Qb, W1b, b1, nullptr, h2, nullptr);
  // out = Q + h2 @ W2^T + b2   (swapped: vector residual + store)
  k_gemm<2, 1, H4, H4, H4, HH><<<dim3(256, 8), 256, 0, stream>>>(
      h2, W2b, b2, Qb, nullptr, out);
}